// Round 1
// baseline (6454.878 us; speedup 1.0000x reference)
//
#include <hip/hip_runtime.h>
#include <math.h>

#define NLEN   32768
#define NATOMS 256
#define ATOM_S 512
#define NSTEPS 16
#define NCHAN  8   // 2 signals x 4 batches

// ---------- packed ordered key helpers ----------
__device__ __forceinline__ unsigned int ord32(float x) {
    unsigned int u = __float_as_uint(x);
    return (u & 0x80000000u) ? ~u : (u | 0x80000000u);
}
__device__ __forceinline__ float unord32(unsigned int o) {
    unsigned int u = (o & 0x80000000u) ? (o & 0x7FFFFFFFu) : ~o;
    return __uint_as_float(u);
}
// bigger key = bigger value, then smaller atom index (matches flat-argmax tie-break)
__device__ __forceinline__ unsigned long long packkey(float v, int a) {
    return ((unsigned long long)ord32(v) << 32) |
           (unsigned long long)(0xFFFFFFFFu - (unsigned int)a);
}

// ---------- prep: normalize dictionary, init residual, zero keys ----------
__global__ void prep_kernel(const float* __restrict__ recon,
                            const float* __restrict__ target,
                            const float* __restrict__ d,
                            float* __restrict__ d_n,
                            float* __restrict__ residual,
                            unsigned long long* __restrict__ mkey) {
    int b = blockIdx.x, t = threadIdx.x;
    if (b < NATOMS) {
        __shared__ float red[256];
        float x0 = d[b * ATOM_S + t];
        float x1 = d[b * ATOM_S + 256 + t];
        red[t] = x0 * x0 + x1 * x1;
        __syncthreads();
        for (int off = 128; off; off >>= 1) {
            if (t < off) red[t] += red[t + off];
            __syncthreads();
        }
        float denom = sqrtf(red[0]) + 1e-8f;
        d_n[b * ATOM_S + t]       = x0 / denom;
        d_n[b * ATOM_S + 256 + t] = x1 / denom;
    } else {
        int blk = b - NATOMS; // 0..31, each handles 8192 elements
        for (int i = 0; i < 32; ++i) {
            int idx = blk * 8192 + i * 256 + t;     // 0 .. 262143
            int c = idx >> 15, q = idx & (NLEN - 1);
            residual[idx] = (c < 4) ? recon[c * NLEN + q] : target[(c - 4) * NLEN + q];
            mkey[idx] = 0ull;
        }
    }
}

// ---------- shared inner dot-product macro body ----------
// computes 4 consecutive-position dots vs one atom row, sliding-window in regs
__device__ __forceinline__ void dot4(const float* __restrict__ lres, int base,
                                     const float4* __restrict__ dp,
                                     float& a0, float& a1, float& a2, float& a3) {
    float4 rc = *(const float4*)&lres[base];
    a0 = 0.f; a1 = 0.f; a2 = 0.f; a3 = 0.f;
#pragma unroll 4
    for (int s4 = 0; s4 < ATOM_S / 4; ++s4) {
        float4 rn = *(const float4*)&lres[base + s4 * 4 + 4];
        float4 dv = dp[s4];
        a0 = fmaf(rc.x, dv.x, a0); a0 = fmaf(rc.y, dv.y, a0);
        a0 = fmaf(rc.z, dv.z, a0); a0 = fmaf(rc.w, dv.w, a0);
        a1 = fmaf(rc.y, dv.x, a1); a1 = fmaf(rc.z, dv.y, a1);
        a1 = fmaf(rc.w, dv.z, a1); a1 = fmaf(rn.x, dv.w, a1);
        a2 = fmaf(rc.z, dv.x, a2); a2 = fmaf(rc.w, dv.y, a2);
        a2 = fmaf(rn.x, dv.z, a2); a2 = fmaf(rn.y, dv.w, a2);
        a3 = fmaf(rc.w, dv.x, a3); a3 = fmaf(rn.x, dv.y, a3);
        a3 = fmaf(rn.y, dv.z, a3); a3 = fmaf(rn.z, dv.w, a3);
        rc = rn;
    }
}

// ---------- initial full correlation + per-position max ----------
// grid (32 tiles, 8 channels, 4 atom-groups of 64), 256 threads, P=4 positions/thread
__global__ __launch_bounds__(256) void init_conv(const float* __restrict__ residual,
                                                 const float* __restrict__ d_n,
                                                 unsigned long long* __restrict__ mkey) {
    __shared__ __align__(16) float lres[1536 + 16];
    int q0 = blockIdx.x * 1024;
    int c  = blockIdx.y;
    int ag = blockIdx.z;
    int t  = threadIdx.x;
    const float* res = residual + c * NLEN;
    for (int i = t; i < 1536; i += 256) {
        int g = q0 + i;
        lres[i] = (g < NLEN) ? res[g] : 0.0f;
    }
    __syncthreads();

    float bestv[4] = {-INFINITY, -INFINITY, -INFINITY, -INFINITY};
    int   besta[4] = {0, 0, 0, 0};
    int base = t * 4;
    for (int a = ag * 64; a < ag * 64 + 64; ++a) {
        const float4* dp = (const float4*)(d_n + a * ATOM_S);
        float a0, a1, a2, a3;
        dot4(lres, base, dp, a0, a1, a2, a3);
        if (a0 > bestv[0]) { bestv[0] = a0; besta[0] = a; }
        if (a1 > bestv[1]) { bestv[1] = a1; besta[1] = a; }
        if (a2 > bestv[2]) { bestv[2] = a2; besta[2] = a; }
        if (a3 > bestv[3]) { bestv[3] = a3; besta[3] = a; }
    }
    unsigned long long* mk = mkey + c * NLEN;
#pragma unroll
    for (int j = 0; j < 4; ++j) {
        int q = q0 + base + j;
        atomicMax(&mk[q], packkey(bestv[j], besta[j]));
    }
}

// ---------- per-step: global argmax scan + residual update + window key-zero ----------
__global__ void select_update(float* __restrict__ residual,
                              const float* __restrict__ d_n,
                              unsigned long long* __restrict__ mkey,
                              int* __restrict__ sel_a, int* __restrict__ sel_p,
                              float* __restrict__ sel_v, int step, int zero_window) {
    int c = blockIdx.x, t = threadIdx.x;
    __shared__ unsigned long long skey[256];
    __shared__ int sq[256];
    const unsigned long long* mk = mkey + c * NLEN;
    unsigned long long bk = 0ull; int bq = 0;
    for (int q = t; q < NLEN; q += 256) {
        unsigned long long k = mk[q];
        if (k > bk) { bk = k; bq = q; }   // ascending q: keeps smallest q on ties
    }
    skey[t] = bk; sq[t] = bq;
    __syncthreads();
    for (int off = 128; off; off >>= 1) {
        if (t < off) {
            if (skey[t + off] > skey[t] ||
                (skey[t + off] == skey[t] && sq[t + off] < sq[t])) {
                skey[t] = skey[t + off]; sq[t] = sq[t + off];
            }
        }
        __syncthreads();
    }
    __shared__ int sa, sp; __shared__ float sv;
    if (t == 0) {
        unsigned long long k = skey[0];
        int a = (int)(0xFFFFFFFFu - (unsigned int)(k & 0xFFFFFFFFull));
        float v = unord32((unsigned int)(k >> 32));
        sa = a; sp = sq[0]; sv = v;
        sel_a[c * NSTEPS + step] = a;
        sel_p[c * NSTEPS + step] = sq[0];
        sel_v[c * NSTEPS + step] = v;
    }
    __syncthreads();
    int a = sa, p = sp; float v = sv;
    float* resc = residual + c * NLEN;
    for (int i = t; i < ATOM_S; i += 256) {
        int q = p + i;
        if (q < NLEN) {
            float prod = __fmul_rn(v, d_n[a * ATOM_S + i]);
            resc[q] = __fsub_rn(resc[q], prod);
        }
    }
    if (zero_window) {
        int w0 = max(0, p - (ATOM_S - 1));
        int w1 = min(NLEN, p + ATOM_S);
        for (int q = w0 + t; q < w1; q += 256) mkey[c * NLEN + q] = 0ull;
    }
}

// ---------- per-step: recompute window maxima from updated residual ----------
// grid (4 pos-tiles of 256, 8 channels, 16 atom-groups of 16), 256 threads
// block: 4 waves x 64 lanes; wave handles 4 atoms, lane handles 4 consecutive positions
__global__ __launch_bounds__(256) void window_conv(const float* __restrict__ residual,
                                                   const float* __restrict__ d_n,
                                                   unsigned long long* __restrict__ mkey,
                                                   const int* __restrict__ sel_p, int step) {
    __shared__ __align__(16) float lres[768 + 16];
    int c = blockIdx.y;
    int p = sel_p[c * NSTEPS + step];
    int w0 = max(0, p - (ATOM_S - 1));
    int w1 = min(NLEN, p + ATOM_S);
    int qstart = w0 + blockIdx.x * 256;
    int t = threadIdx.x;
    const float* res = residual + c * NLEN;
    for (int i = t; i < 768; i += 256) {
        int g = qstart + i;
        lres[i] = (g < NLEN) ? res[g] : 0.0f;
    }
    __syncthreads();

    int wv = t >> 6, l = t & 63;
    int base = l * 4;
    float bestv[4] = {-INFINITY, -INFINITY, -INFINITY, -INFINITY};
    int   besta[4] = {0, 0, 0, 0};
    int a0i = blockIdx.z * 16 + wv * 4;
    for (int a = a0i; a < a0i + 4; ++a) {
        const float4* dp = (const float4*)(d_n + a * ATOM_S);
        float a0, a1, a2, a3;
        dot4(lres, base, dp, a0, a1, a2, a3);
        if (a0 > bestv[0]) { bestv[0] = a0; besta[0] = a; }
        if (a1 > bestv[1]) { bestv[1] = a1; besta[1] = a; }
        if (a2 > bestv[2]) { bestv[2] = a2; besta[2] = a; }
        if (a3 > bestv[3]) { bestv[3] = a3; besta[3] = a; }
    }
    unsigned long long* mk = mkey + c * NLEN;
#pragma unroll
    for (int j = 0; j < 4; ++j) {
        int q = qstart + base + j;
        if (q < w1) atomicMax(&mk[q], packkey(bestv[j], besta[j]));
    }
}

// ---------- final loss from sparse selections (single thread, f64) ----------
__global__ void loss_kernel(const int* __restrict__ sel_a, const int* __restrict__ sel_p,
                            const float* __restrict__ sel_v, float* __restrict__ out) {
    if (threadIdx.x != 0 || blockIdx.x != 0) return;
    int uc[128], ua[128], up[128]; double uv[128]; int n = 0;
    for (int c = 0; c < NCHAN; ++c) {
        for (int k = 0; k < NSTEPS; ++k) {
            int a = sel_a[c * NSTEPS + k], p = sel_p[c * NSTEPS + k];
            double v = (double)sel_v[c * NSTEPS + k];
            int found = -1;
            for (int i = 0; i < n; ++i)
                if (uc[i] == c && ua[i] == a && up[i] == p) { found = i; break; }
            if (found >= 0) uv[found] += v;
            else { uc[n] = c; ua[n] = a; up[n] = p; uv[n] = v; ++n; }
        }
    }
    double mx = 0.0;
    for (int i = 0; i < n; ++i) mx = fmax(mx, uv[i]);

    const double EPS = 1e-12;
    double l1_bg = log1p(-EPS);
    double bg_term = -l1_bg;           // r=0,t=0 element contribution

    bool used[128];
    for (int i = 0; i < n; ++i) used[i] = false;
    double total_extra = 0.0;
    for (int i = 0; i < n; ++i) {
        if (used[i]) continue;
        used[i] = true;
        int b = uc[i] & 3;
        bool is_r = uc[i] < 4;
        double rv = is_r ? uv[i] : 0.0;
        double tv = is_r ? 0.0 : uv[i];
        for (int j = i + 1; j < n; ++j) {
            if (!used[j] && (uc[j] & 3) == b && ((uc[j] < 4) != is_r) &&
                ua[j] == ua[i] && up[j] == up[i]) {
                used[j] = true;
                if (uc[j] < 4) rv = uv[j]; else tv = uv[j];
            }
        }
        double r = rv / mx, tt = tv / mx;
        double rc = r;
        if (rc < EPS) rc = EPS;
        if (rc > 1.0) rc = 1.0;        // f32(1 - 1e-12) == 1.0f
        double lr = log(rc);  if (lr < -100.0) lr = -100.0;
        double l1 = (rc >= 1.0) ? -100.0 : log1p(-rc);
        if (l1 < -100.0) l1 = -100.0;
        double term = -(tt * lr + (1.0 - tt) * l1);
        total_extra += term - bg_term;
    }
    const double count = 33554432.0;   // 4 * 256 * 32768
    double total = count * bg_term + total_extra;
    out[0] = (float)(total / count);
}

// ---------- launch ----------
extern "C" void kernel_launch(void* const* d_in, const int* in_sizes, int n_in,
                              void* d_out, int out_size, void* d_ws, size_t ws_size,
                              hipStream_t stream) {
    const float* recon  = (const float*)d_in[0];
    const float* target = (const float*)d_in[1];
    const float* d      = (const float*)d_in[2];
    char* ws = (char*)d_ws;
    float* d_n                    = (float*)(ws);                 // 524288 B
    float* residual               = (float*)(ws + 524288);        // 1048576 B
    unsigned long long* mkey      = (unsigned long long*)(ws + 1572864); // 2097152 B
    int*   sel_a                  = (int*)(ws + 3670016);
    int*   sel_p                  = (int*)(ws + 3670528);
    float* sel_v                  = (float*)(ws + 3671040);
    float* out = (float*)d_out;

    hipLaunchKernelGGL(prep_kernel, dim3(NATOMS + 32), dim3(256), 0, stream,
                       recon, target, d, d_n, residual, mkey);
    hipLaunchKernelGGL(init_conv, dim3(32, NCHAN, 4), dim3(256), 0, stream,
                       residual, d_n, mkey);
    for (int k = 0; k < NSTEPS; ++k) {
        hipLaunchKernelGGL(select_update, dim3(NCHAN), dim3(256), 0, stream,
                           residual, d_n, mkey, sel_a, sel_p, sel_v, k,
                           (k < NSTEPS - 1) ? 1 : 0);
        if (k < NSTEPS - 1)
            hipLaunchKernelGGL(window_conv, dim3(4, NCHAN, 16), dim3(256), 0, stream,
                               residual, d_n, mkey, sel_p, k);
    }
    hipLaunchKernelGGL(loss_kernel, dim3(1), dim3(1), 0, stream,
                       sel_a, sel_p, sel_v, out);
}

// Round 2
// 3647.435 us; speedup vs baseline: 1.7697x; 1.7697x over previous
//
#include <hip/hip_runtime.h>
#include <math.h>

#define NLEN   32768
#define NATOMS 256
#define ATOM_S 512
#define NSTEPS 16
#define NCHAN  8   // 2 signals x 4 batches
#define NSEL   (NCHAN * NSTEPS)   // 128

// ---------- packed ordered key helpers ----------
__device__ __forceinline__ unsigned int ord32(float x) {
    unsigned int u = __float_as_uint(x);
    return (u & 0x80000000u) ? ~u : (u | 0x80000000u);
}
__device__ __forceinline__ float unord32(unsigned int o) {
    unsigned int u = (o & 0x80000000u) ? (o & 0x7FFFFFFFu) : ~o;
    return __uint_as_float(u);
}
// bigger key = bigger value, then smaller atom index (matches flat-argmax tie-break)
__device__ __forceinline__ unsigned long long packkey(float v, int a) {
    return ((unsigned long long)ord32(v) << 32) |
           (unsigned long long)(0xFFFFFFFFu - (unsigned int)a);
}

// ---------- prep: normalize dictionary, init residual, zero keys ----------
__global__ void prep_kernel(const float* __restrict__ recon,
                            const float* __restrict__ target,
                            const float* __restrict__ d,
                            float* __restrict__ d_n,
                            float* __restrict__ residual,
                            unsigned long long* __restrict__ mkey) {
    int b = blockIdx.x, t = threadIdx.x;
    if (b < NATOMS) {
        __shared__ float red[256];
        float x0 = d[b * ATOM_S + t];
        float x1 = d[b * ATOM_S + 256 + t];
        red[t] = x0 * x0 + x1 * x1;
        __syncthreads();
        for (int off = 128; off; off >>= 1) {
            if (t < off) red[t] += red[t + off];
            __syncthreads();
        }
        float denom = sqrtf(red[0]) + 1e-8f;
        d_n[b * ATOM_S + t]       = x0 / denom;
        d_n[b * ATOM_S + 256 + t] = x1 / denom;
    } else {
        int blk = b - NATOMS; // 0..31, each handles 8192 elements
        for (int i = 0; i < 32; ++i) {
            int idx = blk * 8192 + i * 256 + t;     // 0 .. 262143
            int c = idx >> 15, q = idx & (NLEN - 1);
            residual[idx] = (c < 4) ? recon[c * NLEN + q] : target[(c - 4) * NLEN + q];
            mkey[idx] = 0ull;
        }
    }
}

// ---------- shared inner dot-product body ----------
// computes 4 consecutive-position dots vs one atom row, sliding-window in regs
__device__ __forceinline__ void dot4(const float* __restrict__ lres, int base,
                                     const float4* __restrict__ dp,
                                     float& a0, float& a1, float& a2, float& a3) {
    float4 rc = *(const float4*)&lres[base];
    a0 = 0.f; a1 = 0.f; a2 = 0.f; a3 = 0.f;
#pragma unroll 4
    for (int s4 = 0; s4 < ATOM_S / 4; ++s4) {
        float4 rn = *(const float4*)&lres[base + s4 * 4 + 4];
        float4 dv = dp[s4];
        a0 = fmaf(rc.x, dv.x, a0); a0 = fmaf(rc.y, dv.y, a0);
        a0 = fmaf(rc.z, dv.z, a0); a0 = fmaf(rc.w, dv.w, a0);
        a1 = fmaf(rc.y, dv.x, a1); a1 = fmaf(rc.z, dv.y, a1);
        a1 = fmaf(rc.w, dv.z, a1); a1 = fmaf(rn.x, dv.w, a1);
        a2 = fmaf(rc.z, dv.x, a2); a2 = fmaf(rc.w, dv.y, a2);
        a2 = fmaf(rn.x, dv.z, a2); a2 = fmaf(rn.y, dv.w, a2);
        a3 = fmaf(rc.w, dv.x, a3); a3 = fmaf(rn.x, dv.y, a3);
        a3 = fmaf(rn.y, dv.z, a3); a3 = fmaf(rn.z, dv.w, a3);
        rc = rn;
    }
}

// ---------- initial full correlation + per-position max ----------
__global__ __launch_bounds__(256) void init_conv(const float* __restrict__ residual,
                                                 const float* __restrict__ d_n,
                                                 unsigned long long* __restrict__ mkey) {
    __shared__ __align__(16) float lres[1536 + 16];
    int q0 = blockIdx.x * 1024;
    int c  = blockIdx.y;
    int ag = blockIdx.z;
    int t  = threadIdx.x;
    const float* res = residual + c * NLEN;
    for (int i = t; i < 1536; i += 256) {
        int g = q0 + i;
        lres[i] = (g < NLEN) ? res[g] : 0.0f;
    }
    __syncthreads();

    float bestv[4] = {-INFINITY, -INFINITY, -INFINITY, -INFINITY};
    int   besta[4] = {0, 0, 0, 0};
    int base = t * 4;
    for (int a = ag * 64; a < ag * 64 + 64; ++a) {
        const float4* dp = (const float4*)(d_n + a * ATOM_S);
        float a0, a1, a2, a3;
        dot4(lres, base, dp, a0, a1, a2, a3);
        if (a0 > bestv[0]) { bestv[0] = a0; besta[0] = a; }
        if (a1 > bestv[1]) { bestv[1] = a1; besta[1] = a; }
        if (a2 > bestv[2]) { bestv[2] = a2; besta[2] = a; }
        if (a3 > bestv[3]) { bestv[3] = a3; besta[3] = a; }
    }
    unsigned long long* mk = mkey + c * NLEN;
#pragma unroll
    for (int j = 0; j < 4; ++j) {
        int q = q0 + base + j;
        atomicMax(&mk[q], packkey(bestv[j], besta[j]));
    }
}

// ---------- per-step: global argmax scan + residual update + window key-zero ----------
__global__ void select_update(float* __restrict__ residual,
                              const float* __restrict__ d_n,
                              unsigned long long* __restrict__ mkey,
                              int* __restrict__ sel_a, int* __restrict__ sel_p,
                              float* __restrict__ sel_v, int step, int zero_window) {
    int c = blockIdx.x, t = threadIdx.x;
    __shared__ unsigned long long skey[256];
    __shared__ int sq[256];
    const unsigned long long* mk = mkey + c * NLEN;
    unsigned long long bk = 0ull; int bq = 0;
    for (int q = t; q < NLEN; q += 256) {
        unsigned long long k = mk[q];
        if (k > bk) { bk = k; bq = q; }   // ascending q: keeps smallest q on ties
    }
    skey[t] = bk; sq[t] = bq;
    __syncthreads();
    for (int off = 128; off; off >>= 1) {
        if (t < off) {
            if (skey[t + off] > skey[t] ||
                (skey[t + off] == skey[t] && sq[t + off] < sq[t])) {
                skey[t] = skey[t + off]; sq[t] = sq[t + off];
            }
        }
        __syncthreads();
    }
    __shared__ int sa, sp; __shared__ float sv;
    if (t == 0) {
        unsigned long long k = skey[0];
        int a = (int)(0xFFFFFFFFu - (unsigned int)(k & 0xFFFFFFFFull));
        float v = unord32((unsigned int)(k >> 32));
        sa = a; sp = sq[0]; sv = v;
        sel_a[c * NSTEPS + step] = a;
        sel_p[c * NSTEPS + step] = sq[0];
        sel_v[c * NSTEPS + step] = v;
    }
    __syncthreads();
    int a = sa, p = sp; float v = sv;
    float* resc = residual + c * NLEN;
    for (int i = t; i < ATOM_S; i += 256) {
        int q = p + i;
        if (q < NLEN) {
            float prod = __fmul_rn(v, d_n[a * ATOM_S + i]);
            resc[q] = __fsub_rn(resc[q], prod);
        }
    }
    if (zero_window) {
        int w0 = max(0, p - (ATOM_S - 1));
        int w1 = min(NLEN, p + ATOM_S);
        for (int q = w0 + t; q < w1; q += 256) mkey[c * NLEN + q] = 0ull;
    }
}

// ---------- per-step: recompute window maxima from updated residual ----------
__global__ __launch_bounds__(256) void window_conv(const float* __restrict__ residual,
                                                   const float* __restrict__ d_n,
                                                   unsigned long long* __restrict__ mkey,
                                                   const int* __restrict__ sel_p, int step) {
    __shared__ __align__(16) float lres[768 + 16];
    int c = blockIdx.y;
    int p = sel_p[c * NSTEPS + step];
    int w0 = max(0, p - (ATOM_S - 1));
    int w1 = min(NLEN, p + ATOM_S);
    int qstart = w0 + blockIdx.x * 256;
    int t = threadIdx.x;
    const float* res = residual + c * NLEN;
    for (int i = t; i < 768; i += 256) {
        int g = qstart + i;
        lres[i] = (g < NLEN) ? res[g] : 0.0f;
    }
    __syncthreads();

    int wv = t >> 6, l = t & 63;
    int base = l * 4;
    float bestv[4] = {-INFINITY, -INFINITY, -INFINITY, -INFINITY};
    int   besta[4] = {0, 0, 0, 0};
    int a0i = blockIdx.z * 16 + wv * 4;
    for (int a = a0i; a < a0i + 4; ++a) {
        const float4* dp = (const float4*)(d_n + a * ATOM_S);
        float a0, a1, a2, a3;
        dot4(lres, base, dp, a0, a1, a2, a3);
        if (a0 > bestv[0]) { bestv[0] = a0; besta[0] = a; }
        if (a1 > bestv[1]) { bestv[1] = a1; besta[1] = a; }
        if (a2 > bestv[2]) { bestv[2] = a2; besta[2] = a; }
        if (a3 > bestv[3]) { bestv[3] = a3; besta[3] = a; }
    }
    unsigned long long* mk = mkey + c * NLEN;
#pragma unroll
    for (int j = 0; j < 4; ++j) {
        int q = qstart + base + j;
        if (q < w1) atomicMax(&mk[q], packkey(bestv[j], besta[j]));
    }
}

// ---------- final loss from sparse selections: PARALLEL (128 threads, LDS only) ----------
__global__ __launch_bounds__(128) void loss_kernel(const int* __restrict__ sel_a,
                                                   const int* __restrict__ sel_p,
                                                   const float* __restrict__ sel_v,
                                                   float* __restrict__ out) {
    int t = threadIdx.x;                  // 0..127, one per selection entry
    __shared__ int sc[NSEL], sa[NSEL], sp[NSEL];
    __shared__ double sv[NSEL];
    __shared__ double red[NSEL];
    __shared__ double smx;

    sc[t] = t / NSTEPS;                   // channel (0..7); entry t = (c,k) in scan order
    sa[t] = sel_a[t];
    sp[t] = sel_p[t];
    sv[t] = (double)sel_v[t];
    __syncthreads();

    int  myc = sc[t], mya = sa[t], myp = sp[t];
    int  myb = myc & 3;

    // --- per-(c,a,p) dedup: owner = smallest index with same full key; sum v ---
    int fullowner = t;
    double fullsum = 0.0;
    for (int j = 0; j < NSEL; ++j) {
        if (sc[j] == myc && sa[j] == mya && sp[j] == myp) {
            if (j < fullowner) fullowner = j;
            fullsum += sv[j];
        }
    }

    // --- mx = max(0, max over unique-(c,a,p) sums) ---
    red[t] = (fullowner == t) ? fullsum : 0.0;
    __syncthreads();
    for (int off = 64; off; off >>= 1) {
        if (t < off) red[t] = fmax(red[t], red[t + off]);
        __syncthreads();
    }
    if (t == 0) smx = red[0];
    __syncthreads();
    double mx = smx;

    // --- per-(b,a,p) group across r/t halves: owner computes the BCE term ---
    int gowner = t;
    double rv = 0.0, tv = 0.0;
    for (int j = 0; j < NSEL; ++j) {
        if ((sc[j] & 3) == myb && sa[j] == mya && sp[j] == myp) {
            if (j < gowner) gowner = j;
            if (sc[j] < 4) rv += sv[j]; else tv += sv[j];
        }
    }

    const double EPS = 1e-12;
    double bg_term = -log1p(-EPS);        // contribution of an r=0,t=0 element

    double extra = 0.0;
    if (gowner == t) {
        double r = rv / mx, tt = tv / mx;
        double rc = r;
        if (rc < EPS) rc = EPS;
        if (rc > 1.0) rc = 1.0;           // f32(1 - 1e-12) == 1.0f
        double lr = log(rc);  if (lr < -100.0) lr = -100.0;
        double l1 = (rc >= 1.0) ? -100.0 : log1p(-rc);
        if (l1 < -100.0) l1 = -100.0;
        double term = -(tt * lr + (1.0 - tt) * l1);
        extra = term - bg_term;
    }

    red[t] = extra;
    __syncthreads();
    for (int off = 64; off; off >>= 1) {
        if (t < off) red[t] += red[t + off];
        __syncthreads();
    }
    if (t == 0) {
        const double count = 33554432.0;  // 4 * 256 * 32768
        double total = count * bg_term + red[0];
        out[0] = (float)(total / count);
    }
}

// ---------- launch ----------
extern "C" void kernel_launch(void* const* d_in, const int* in_sizes, int n_in,
                              void* d_out, int out_size, void* d_ws, size_t ws_size,
                              hipStream_t stream) {
    const float* recon  = (const float*)d_in[0];
    const float* target = (const float*)d_in[1];
    const float* d      = (const float*)d_in[2];
    char* ws = (char*)d_ws;
    float* d_n                    = (float*)(ws);                 // 524288 B
    float* residual               = (float*)(ws + 524288);        // 1048576 B
    unsigned long long* mkey      = (unsigned long long*)(ws + 1572864); // 2097152 B
    int*   sel_a                  = (int*)(ws + 3670016);
    int*   sel_p                  = (int*)(ws + 3670528);
    float* sel_v                  = (float*)(ws + 3671040);
    float* out = (float*)d_out;

    hipLaunchKernelGGL(prep_kernel, dim3(NATOMS + 32), dim3(256), 0, stream,
                       recon, target, d, d_n, residual, mkey);
    hipLaunchKernelGGL(init_conv, dim3(32, NCHAN, 4), dim3(256), 0, stream,
                       residual, d_n, mkey);
    for (int k = 0; k < NSTEPS; ++k) {
        hipLaunchKernelGGL(select_update, dim3(NCHAN), dim3(256), 0, stream,
                           residual, d_n, mkey, sel_a, sel_p, sel_v, k,
                           (k < NSTEPS - 1) ? 1 : 0);
        if (k < NSTEPS - 1)
            hipLaunchKernelGGL(window_conv, dim3(4, NCHAN, 16), dim3(256), 0, stream,
                               residual, d_n, mkey, sel_p, k);
    }
    hipLaunchKernelGGL(loss_kernel, dim3(1), dim3(128), 0, stream,
                       sel_a, sel_p, sel_v, out);
}

// Round 3
// 2002.878 us; speedup vs baseline: 3.2228x; 1.8211x over previous
//
#include <hip/hip_runtime.h>
#include <math.h>

#define NLEN   32768
#define NATOMS 256
#define ATOM_S 512
#define NSTEPS 16
#define NCHAN  8   // 2 signals x 4 batches
#define NSEL   (NCHAN * NSTEPS)   // 128

// ---------- packed ordered key helpers ----------
__device__ __forceinline__ unsigned int ord32(float x) {
    unsigned int u = __float_as_uint(x);
    return (u & 0x80000000u) ? ~u : (u | 0x80000000u);
}
__device__ __forceinline__ float unord32(unsigned int o) {
    unsigned int u = (o & 0x80000000u) ? (o & 0x7FFFFFFFu) : ~o;
    return __uint_as_float(u);
}
// bigger key = bigger v, then smaller atom, then smaller position
// (matches argmax over flat index a*NLEN+q, first occurrence)
__device__ __forceinline__ unsigned long long packkey(float v, int a, int q) {
    return ((unsigned long long)ord32(v) << 23)
         | ((unsigned long long)((255 - a) & 255) << 15)
         | (unsigned long long)((NLEN - 1 - q) & 32767);
}

// ---------- prep: normalize dict (transposed layout), init residual/keys ----------
// d_t[(s4*NATOMS + a)*4 + j] = d_n[a][4*s4+j]
__global__ void prep_kernel(const float* __restrict__ recon,
                            const float* __restrict__ target,
                            const float* __restrict__ d,
                            float* __restrict__ d_t,
                            float* __restrict__ residual,
                            unsigned long long* __restrict__ mkey,
                            unsigned long long* __restrict__ stepkey) {
    int b = blockIdx.x, t = threadIdx.x;
    if (b < NATOMS) {
        __shared__ float red[256];
        float x0 = d[b * ATOM_S + t];
        float x1 = d[b * ATOM_S + 256 + t];
        red[t] = x0 * x0 + x1 * x1;
        __syncthreads();
        for (int off = 128; off; off >>= 1) {
            if (t < off) red[t] += red[t + off];
            __syncthreads();
        }
        float denom = sqrtf(red[0]) + 1e-8f;
        int s0 = t, s1 = t + 256;
        d_t[((s0 >> 2) * NATOMS + b) * 4 + (s0 & 3)] = x0 / denom;
        d_t[((s1 >> 2) * NATOMS + b) * 4 + (s1 & 3)] = x1 / denom;
    } else if (b < NATOMS + 32) {
        int blk = b - NATOMS; // 0..31, each handles 8192 elements
        for (int i = 0; i < 32; ++i) {
            int idx = blk * 8192 + i * 256 + t;     // 0 .. 262143
            int c = idx >> 15, q = idx & (NLEN - 1);
            residual[idx] = (c < 4) ? recon[c * NLEN + q] : target[(c - 4) * NLEN + q];
            mkey[idx] = 0ull;
        }
    } else {
        if (t < NSEL) stepkey[t] = 0ull;
    }
}

// ---------- 8-atom sliding-window dot: 128 FMAs per LDS float4 read ----------
// lane covers positions base..base+3; atoms a0..a0+7; accumulates acc[8][4]
__device__ __forceinline__ void dot8(const float* __restrict__ lres, int base,
                                     const float4* __restrict__ dt0, // row s4=0, atom a0
                                     float acc[8][4]) {
#pragma unroll
    for (int aa = 0; aa < 8; ++aa)
#pragma unroll
        for (int j = 0; j < 4; ++j) acc[aa][j] = 0.0f;
    float4 rc = *(const float4*)&lres[base];
    const float4* dt = dt0;
#pragma unroll 1
    for (int s4 = 0; s4 < ATOM_S / 4; ++s4) {
        float4 rn = *(const float4*)&lres[base + s4 * 4 + 4];
#pragma unroll
        for (int aa = 0; aa < 8; ++aa) {
            float4 dv = dt[aa];
            acc[aa][0] = fmaf(rc.x, dv.x, acc[aa][0]);
            acc[aa][0] = fmaf(rc.y, dv.y, acc[aa][0]);
            acc[aa][0] = fmaf(rc.z, dv.z, acc[aa][0]);
            acc[aa][0] = fmaf(rc.w, dv.w, acc[aa][0]);
            acc[aa][1] = fmaf(rc.y, dv.x, acc[aa][1]);
            acc[aa][1] = fmaf(rc.z, dv.y, acc[aa][1]);
            acc[aa][1] = fmaf(rc.w, dv.z, acc[aa][1]);
            acc[aa][1] = fmaf(rn.x, dv.w, acc[aa][1]);
            acc[aa][2] = fmaf(rc.z, dv.x, acc[aa][2]);
            acc[aa][2] = fmaf(rc.w, dv.y, acc[aa][2]);
            acc[aa][2] = fmaf(rn.x, dv.z, acc[aa][2]);
            acc[aa][2] = fmaf(rn.y, dv.w, acc[aa][2]);
            acc[aa][3] = fmaf(rc.w, dv.x, acc[aa][3]);
            acc[aa][3] = fmaf(rn.x, dv.y, acc[aa][3]);
            acc[aa][3] = fmaf(rn.y, dv.z, acc[aa][3]);
            acc[aa][3] = fmaf(rn.z, dv.w, acc[aa][3]);
        }
        dt += NATOMS;    // next s4 row of transposed dict
        rc = rn;
    }
}

// ---------- initial full correlation + per-position max ----------
// grid (32 tiles of 1024 pos, 8 channels, 4 atom-groups of 64), 256 threads
__global__ __launch_bounds__(256) void init_conv(const float* __restrict__ residual,
                                                 const float* __restrict__ d_t,
                                                 unsigned long long* __restrict__ mkey) {
    __shared__ __align__(16) float lres[1536 + 16];
    int q0 = blockIdx.x * 1024;
    int c  = blockIdx.y;
    int ag = blockIdx.z;
    int t  = threadIdx.x;
    const float* res = residual + c * NLEN;
    for (int i = t; i < 1536; i += 256) {
        int g = q0 + i;
        lres[i] = (g < NLEN) ? res[g] : 0.0f;
    }
    __syncthreads();

    int base = t * 4;
    float bestv[4] = {-INFINITY, -INFINITY, -INFINITY, -INFINITY};
    int   besta[4] = {0, 0, 0, 0};
#pragma unroll 1
    for (int g8 = 0; g8 < 8; ++g8) {
        int a0 = ag * 64 + g8 * 8;
        float acc[8][4];
        dot8(lres, base, (const float4*)d_t + a0, acc);
#pragma unroll
        for (int aa = 0; aa < 8; ++aa)
#pragma unroll
            for (int j = 0; j < 4; ++j)
                if (acc[aa][j] > bestv[j]) { bestv[j] = acc[aa][j]; besta[j] = a0 + aa; }
    }
    unsigned long long* mk = mkey + c * NLEN;
#pragma unroll
    for (int j = 0; j < 4; ++j) {
        int q = q0 + base + j;
        atomicMax(&mk[q], packkey(bestv[j], besta[j], q));
    }
}

// ---------- per-step: parallel argmax scan (key embeds v,a,q) ----------
// grid (16 seg-blocks, 8 channels), 256 threads
__global__ void argmax_scan(const unsigned long long* __restrict__ mkey,
                            unsigned long long* __restrict__ stepkey, int step) {
    int c = blockIdx.y, t = threadIdx.x;
    const unsigned long long* mk = mkey + c * NLEN;
    int q0 = blockIdx.x * 2048;
    unsigned long long bk = 0ull;
#pragma unroll
    for (int i = 0; i < 8; ++i) {
        unsigned long long k = mk[q0 + i * 256 + t];
        if (k > bk) bk = k;
    }
    __shared__ unsigned long long red[256];
    red[t] = bk;
    __syncthreads();
    for (int off = 128; off; off >>= 1) {
        if (t < off) { if (red[t + off] > red[t]) red[t] = red[t + off]; }
        __syncthreads();
    }
    if (t == 0) atomicMax(&stepkey[step * NCHAN + c], red[0]);
}

// ---------- per-step: decode selection, update residual, zero key window ----------
__global__ void finish_step(float* __restrict__ residual,
                            const float* __restrict__ d_t,
                            unsigned long long* __restrict__ mkey,
                            const unsigned long long* __restrict__ stepkey,
                            int* __restrict__ sel_a, int* __restrict__ sel_p,
                            float* __restrict__ sel_v, int step, int zero_window) {
    int c = blockIdx.x, t = threadIdx.x;
    unsigned long long k = stepkey[step * NCHAN + c];
    int a = 255 - (int)((k >> 15) & 255);
    int p = (NLEN - 1) - (int)(k & 32767);
    float v = unord32((unsigned int)(k >> 23));
    if (t == 0) {
        sel_a[c * NSTEPS + step] = a;
        sel_p[c * NSTEPS + step] = p;
        sel_v[c * NSTEPS + step] = v;
    }
    float* resc = residual + c * NLEN;
    for (int i = t; i < ATOM_S; i += 256) {
        int q = p + i;
        if (q < NLEN) {
            float dval = d_t[((i >> 2) * NATOMS + a) * 4 + (i & 3)];
            resc[q] = __fsub_rn(resc[q], __fmul_rn(v, dval));
        }
    }
    if (zero_window) {
        int w0 = max(0, p - (ATOM_S - 1));
        int w1 = min(NLEN, p + ATOM_S);
        for (int q = w0 + t; q < w1; q += 256) mkey[c * NLEN + q] = 0ull;
    }
}

// ---------- per-step: recompute window maxima from updated residual ----------
// grid (4 pos-tiles of 256, 8 channels, 8 atom-groups of 32), 256 threads
// 4 waves; each wave handles 8 atoms, each lane 4 consecutive positions
__global__ __launch_bounds__(256) void window_conv(const float* __restrict__ residual,
                                                   const float* __restrict__ d_t,
                                                   unsigned long long* __restrict__ mkey,
                                                   const int* __restrict__ sel_p, int step) {
    __shared__ __align__(16) float lres[768 + 16];
    int c = blockIdx.y;
    int p = sel_p[c * NSTEPS + step];
    int w0 = max(0, p - (ATOM_S - 1));
    int w1 = min(NLEN, p + ATOM_S);
    int qstart = w0 + blockIdx.x * 256;
    int t = threadIdx.x;
    const float* res = residual + c * NLEN;
    for (int i = t; i < 768; i += 256) {
        int g = qstart + i;
        lres[i] = (g < NLEN) ? res[g] : 0.0f;
    }
    __syncthreads();

    int wv = t >> 6, l = t & 63;
    int base = l * 4;
    int a0 = blockIdx.z * 32 + wv * 8;
    float acc[8][4];
    dot8(lres, base, (const float4*)d_t + a0, acc);

    float bestv[4] = {-INFINITY, -INFINITY, -INFINITY, -INFINITY};
    int   besta[4] = {0, 0, 0, 0};
#pragma unroll
    for (int aa = 0; aa < 8; ++aa)
#pragma unroll
        for (int j = 0; j < 4; ++j)
            if (acc[aa][j] > bestv[j]) { bestv[j] = acc[aa][j]; besta[j] = a0 + aa; }

    unsigned long long* mk = mkey + c * NLEN;
#pragma unroll
    for (int j = 0; j < 4; ++j) {
        int q = qstart + base + j;
        if (q < w1) atomicMax(&mk[q], packkey(bestv[j], besta[j], q));
    }
}

// ---------- final loss from sparse selections: PARALLEL (128 threads, LDS only) ----------
__global__ __launch_bounds__(128) void loss_kernel(const int* __restrict__ sel_a,
                                                   const int* __restrict__ sel_p,
                                                   const float* __restrict__ sel_v,
                                                   float* __restrict__ out) {
    int t = threadIdx.x;                  // 0..127, one per selection entry
    __shared__ int sc[NSEL], sa[NSEL], sp[NSEL];
    __shared__ double sv[NSEL];
    __shared__ double red[NSEL];
    __shared__ double smx;

    sc[t] = t / NSTEPS;                   // channel (0..7)
    sa[t] = sel_a[t];
    sp[t] = sel_p[t];
    sv[t] = (double)sel_v[t];
    __syncthreads();

    int  myc = sc[t], mya = sa[t], myp = sp[t];
    int  myb = myc & 3;

    int fullowner = t;
    double fullsum = 0.0;
    for (int j = 0; j < NSEL; ++j) {
        if (sc[j] == myc && sa[j] == mya && sp[j] == myp) {
            if (j < fullowner) fullowner = j;
            fullsum += sv[j];
        }
    }

    red[t] = (fullowner == t) ? fullsum : 0.0;
    __syncthreads();
    for (int off = 64; off; off >>= 1) {
        if (t < off) red[t] = fmax(red[t], red[t + off]);
        __syncthreads();
    }
    if (t == 0) smx = red[0];
    __syncthreads();
    double mx = smx;

    int gowner = t;
    double rv = 0.0, tv = 0.0;
    for (int j = 0; j < NSEL; ++j) {
        if ((sc[j] & 3) == myb && sa[j] == mya && sp[j] == myp) {
            if (j < gowner) gowner = j;
            if (sc[j] < 4) rv += sv[j]; else tv += sv[j];
        }
    }

    const double EPS = 1e-12;
    double bg_term = -log1p(-EPS);

    double extra = 0.0;
    if (gowner == t) {
        double r = rv / mx, tt = tv / mx;
        double rc = r;
        if (rc < EPS) rc = EPS;
        if (rc > 1.0) rc = 1.0;
        double lr = log(rc);  if (lr < -100.0) lr = -100.0;
        double l1 = (rc >= 1.0) ? -100.0 : log1p(-rc);
        if (l1 < -100.0) l1 = -100.0;
        double term = -(tt * lr + (1.0 - tt) * l1);
        extra = term - bg_term;
    }

    red[t] = extra;
    __syncthreads();
    for (int off = 64; off; off >>= 1) {
        if (t < off) red[t] += red[t + off];
        __syncthreads();
    }
    if (t == 0) {
        const double count = 33554432.0;  // 4 * 256 * 32768
        double total = count * bg_term + red[0];
        out[0] = (float)(total / count);
    }
}

// ---------- launch ----------
extern "C" void kernel_launch(void* const* d_in, const int* in_sizes, int n_in,
                              void* d_out, int out_size, void* d_ws, size_t ws_size,
                              hipStream_t stream) {
    const float* recon  = (const float*)d_in[0];
    const float* target = (const float*)d_in[1];
    const float* d      = (const float*)d_in[2];
    char* ws = (char*)d_ws;
    float* d_t                    = (float*)(ws);                        // 524288 B
    float* residual               = (float*)(ws + 524288);               // 1048576 B
    unsigned long long* mkey      = (unsigned long long*)(ws + 1572864); // 2097152 B
    int*   sel_a                  = (int*)(ws + 3670016);
    int*   sel_p                  = (int*)(ws + 3670528);
    float* sel_v                  = (float*)(ws + 3671040);
    unsigned long long* stepkey   = (unsigned long long*)(ws + 3671552); // 1024 B
    float* out = (float*)d_out;

    hipLaunchKernelGGL(prep_kernel, dim3(NATOMS + 33), dim3(256), 0, stream,
                       recon, target, d, d_t, residual, mkey, stepkey);
    hipLaunchKernelGGL(init_conv, dim3(32, NCHAN, 4), dim3(256), 0, stream,
                       residual, d_t, mkey);
    for (int k = 0; k < NSTEPS; ++k) {
        hipLaunchKernelGGL(argmax_scan, dim3(16, NCHAN), dim3(256), 0, stream,
                           mkey, stepkey, k);
        hipLaunchKernelGGL(finish_step, dim3(NCHAN), dim3(256), 0, stream,
                           residual, d_t, mkey, stepkey, sel_a, sel_p, sel_v, k,
                           (k < NSTEPS - 1) ? 1 : 0);
        if (k < NSTEPS - 1)
            hipLaunchKernelGGL(window_conv, dim3(4, NCHAN, 8), dim3(256), 0, stream,
                               residual, d_t, mkey, sel_p, k);
    }
    hipLaunchKernelGGL(loss_kernel, dim3(1), dim3(128), 0, stream,
                       sel_a, sel_p, sel_v, out);
}